// Round 4
// baseline (861.003 us; speedup 1.0000x reference)
//
#include <hip/hip_runtime.h>
#include <stdint.h>

#define L_DIM 2048
#define B_DIM 32
#define D_DIM 1024
#define N_DIM 3072   // 3*D
#define K_DIM 1024
#define BD    32768  // B*D
#define S3    (32 * N_DIM)  // u3 step stride (elems)

typedef __bf16 bf16x8 __attribute__((ext_vector_type(8)));
typedef unsigned short ushort8 __attribute__((ext_vector_type(8)));
typedef float f32x4 __attribute__((ext_vector_type(4)));

typedef const __attribute__((address_space(1))) unsigned int* gq_t;
typedef __attribute__((address_space(3))) unsigned int* lq_t;

static __device__ __forceinline__ unsigned short f2bf(float f) {
  unsigned u = __float_as_uint(f);
  u += 0x7FFFu + ((u >> 16) & 1u);   // RNE
  return (unsigned short)(u >> 16);
}

static __device__ __forceinline__ float bf2f(unsigned short s) {
  return __uint_as_float(((unsigned)s) << 16);
}

// ---------- convert x chunk (f32) -> bf16, 8 elems/thread ----------
__global__ void k_convx(const float* __restrict__ x, unsigned short* __restrict__ xb, int n8) {
  int i = blockIdx.x * blockDim.x + threadIdx.x;
  if (i >= n8) return;
  const float4* p = reinterpret_cast<const float4*>(x) + (size_t)i * 2;
  float4 a = p[0], b = p[1];
  ushort8 o;
  o[0] = f2bf(a.x); o[1] = f2bf(a.y); o[2] = f2bf(a.z); o[3] = f2bf(a.w);
  o[4] = f2bf(b.x); o[5] = f2bf(b.y); o[6] = f2bf(b.z); o[7] = f2bf(b.w);
  reinterpret_cast<ushort8*>(xb)[i] = o;
}

// ---------- W (K,N=3072 interleaved 3d+k) f32 -> WT (N'=k*D+d, K) bf16 ----------
__global__ __launch_bounds__(256) void k_wt(const float* __restrict__ w, unsigned short* __restrict__ wt) {
  __shared__ unsigned short tile[64][65];
  const int bid = blockIdx.x;
  const int kb = bid & 15;          // K/64 tile
  const int db = (bid >> 4) & 15;   // D/64 tile
  const int kp = bid >> 8;          // plane 0..2
  const int t = threadIdx.x;
  const int c = t & 63;
  const int q = t >> 6;             // 0..3
#pragma unroll
  for (int i = 0; i < 16; ++i) {
    int r = q * 16 + i;             // k within tile
    float v = w[(size_t)(kb * 64 + r) * N_DIM + 3 * (db * 64 + c) + kp];
    tile[r][c] = f2bf(v);
  }
  __syncthreads();
  const int k = t & 63;
#pragma unroll
  for (int i = 0; i < 16; ++i) {
    int n = q * 16 + i;             // d within tile
    wt[(size_t)(kp * D_DIM + db * 64 + n) * K_DIM + kb * 64 + k] = tile[k][n];
  }
}

// ---------- per-column bias, plane layout: col j = k*D+d ----------
__global__ void k_biascol(const float* __restrict__ bias, float* __restrict__ bc) {
  int j = blockIdx.x * blockDim.x + threadIdx.x;
  if (j >= N_DIM) return;
  int k = j >> 10;
  int d = j & 1023;
  float v = 0.f;
  if (k == 1) v = bias[d];
  else if (k == 2) v = bias[D_DIM + d];
  bc[j] = v;
}

// ---------- 256x256 8-phase bf16 MFMA GEMM (T1+T2+T3+T4+T5) ----------
__global__ __launch_bounds__(512, 2) void k_gemm(
    const unsigned short* __restrict__ A,
    const unsigned short* __restrict__ BT,
    const float* __restrict__ bc,
    unsigned short* __restrict__ C,
    int Mtiles)
{
  __shared__ unsigned short smem[65536];

  // --- block swizzle (bijective, 8 XCDs) ---
  const int nwg = gridDim.x;
  const int q8 = nwg >> 3, r8 = nwg & 7;
  const int xcd = blockIdx.x & 7, li = blockIdx.x >> 3;
  const int wg = (xcd < r8 ? xcd * (q8 + 1) : r8 * (q8 + 1) + (xcd - r8) * q8) + li;
  const int bm = wg % Mtiles;
  const int bn = wg / Mtiles;

  const int t  = threadIdx.x;
  const int w  = t >> 6;
  const int l  = t & 63;
  const int wr = w >> 2, wc = w & 3;
  const int wrb = wr * 128, wcb = wc * 64;
  const int l15 = l & 15, lg = l >> 4, lx = l & 7;
  const int kgp0 = (lg ^ lx) * 8;          // elem offset of ksub=0 octet
  const int kgp1 = ((4 + lg) ^ lx) * 8;    // ksub=1
  const int sr0 = w * 8 + (l >> 3);        // staging row within half
  const int kgs = (lx ^ (l >> 3)) * 8;     // swizzled source k-octet

  const unsigned short* Abase = A  + (size_t)(bm * 256) * K_DIM;
  const unsigned short* Bbase = BT + (size_t)(bn * 256) * K_DIM;

  f32x4 acc[8][4];
#pragma unroll
  for (int i = 0; i < 8; ++i)
#pragma unroll
    for (int j = 0; j < 4; ++j) acc[i][j] = f32x4{0.f, 0.f, 0.f, 0.f};

#define STAGE(G, growbase, T, ldsBase)                                                  \
  { const unsigned short* s0_ = (G) + (((size_t)((growbase) + sr0)) << 10) + (T) * 64 + kgs; \
    __builtin_amdgcn_global_load_lds((gq_t)s0_, (lq_t)&smem[(ldsBase) + w * 512], 16, 0, 0); \
    const unsigned short* s1_ = s0_ + (64 << 10);                                       \
    __builtin_amdgcn_global_load_lds((gq_t)s1_, (lq_t)&smem[(ldsBase) + 4096 + w * 512], 16, 0, 0); }

#define SB0(T, b) STAGE(Bbase, 0,   (T), (b) * 32768 + 16384)
#define SB1(T, b) STAGE(Bbase, 128, (T), (b) * 32768 + 16384 + 8192)
#define SA0(T, b) STAGE(Abase, 0,   (T), (b) * 32768)
#define SA1(T, b) STAGE(Abase, 128, (T), (b) * 32768 + 8192)

#define LDF(idx) __builtin_bit_cast(bf16x8, *reinterpret_cast<const ushort8*>(&smem[(idx)]))

  // ---- prologue: tile0 fully + SB0(1); wait tile0, SB0(1) stays in flight
  SB0(0, 0); SB1(0, 0); SA0(0, 0); SA1(0, 0); SB0(1, 1);
  asm volatile("s_waitcnt vmcnt(2)" ::: "memory");
  __builtin_amdgcn_s_barrier();

#pragma unroll 2
  for (int t0 = 0; t0 < 16; ++t0) {
    const int cur = t0 & 1, nxt = cur ^ 1;
    const int cA = cur * 32768, cB = cA + 16384;
    bf16x8 bfr[4][2];
#pragma unroll
    for (int q = 0; q < 4; ++q) {
      bf16x8 af[2][2];
      if (q == 0) {
#pragma unroll
        for (int nf = 0; nf < 4; ++nf) {
          const int nr = (wcb + nf * 16 + l15) * 64;
          bfr[nf][0] = LDF(cB + nr + kgp0);
          bfr[nf][1] = LDF(cB + nr + kgp1);
        }
      }
#pragma unroll
      for (int mf = 0; mf < 2; ++mf) {
        const int ar = (wrb + (q * 2 + mf) * 16 + l15) * 64;
        af[mf][0] = LDF(cA + ar + kgp0);
        af[mf][1] = LDF(cA + ar + kgp1);
      }
      if (q == 0 && t0 < 15) SB1(t0 + 1, nxt);
      if (q == 1 && t0 < 15) SA0(t0 + 1, nxt);
      if (q == 2 && t0 < 15) SA1(t0 + 1, nxt);
      if (q == 3 && t0 < 14) SB0(t0 + 2, cur);

      __builtin_amdgcn_s_barrier();
      __builtin_amdgcn_s_setprio(1);
#pragma unroll
      for (int mf = 0; mf < 2; ++mf)
#pragma unroll
        for (int nf = 0; nf < 4; ++nf) {
          acc[q * 2 + mf][nf] = __builtin_amdgcn_mfma_f32_16x16x32_bf16(af[mf][0], bfr[nf][0], acc[q * 2 + mf][nf], 0, 0, 0);
          acc[q * 2 + mf][nf] = __builtin_amdgcn_mfma_f32_16x16x32_bf16(af[mf][1], bfr[nf][1], acc[q * 2 + mf][nf], 0, 0, 0);
        }
      __builtin_amdgcn_s_setprio(0);
      if (q == 3) {
        if (t0 < 14)       asm volatile("s_waitcnt vmcnt(2)" ::: "memory");
        else if (t0 == 14) asm volatile("s_waitcnt vmcnt(0)" ::: "memory");
      }
      __builtin_amdgcn_s_barrier();
      __builtin_amdgcn_sched_barrier(0);
    }
  }

  // ---- epilogue: bias add, f32->bf16, LDS transpose, coalesced 16B stores ----
  // per-wave LDS slice: 64 rows x 72 ushorts (144B padded stride), base w*4608
  __syncthreads();   // all waves past loop; smem fully dead
  float badd[4];
#pragma unroll
  for (int nf = 0; nf < 4; ++nf) badd[nf] = bc[bn * 256 + wcb + nf * 16 + l15];
  const int SLu = w * 4608;
  const int er = l >> 3, ej = l & 7;  // read/store mapping: 8 lanes per row
#pragma unroll
  for (int p = 0; p < 2; ++p) {
#pragma unroll
    for (int fm2 = 0; fm2 < 4; ++fm2)
#pragma unroll
      for (int nf = 0; nf < 4; ++nf)
#pragma unroll
        for (int i = 0; i < 4; ++i) {
          const int lr = fm2 * 16 + lg * 4 + i;
          smem[SLu + lr * 72 + nf * 16 + l15] = f2bf(acc[p * 4 + fm2][nf][i] + badd[nf]);
        }
    // wave-local drain handled by compiler's lgkm dependence tracking
#pragma unroll
    for (int i2 = 0; i2 < 8; ++i2) {
      const int row2 = er + i2 * 8;
      ushort8 v = *reinterpret_cast<const ushort8*>(&smem[SLu + row2 * 72 + ej * 8]);
      const int grow = bm * 256 + wrb + p * 64 + row2;
      const int gcol = bn * 256 + wcb + ej * 8;
      *reinterpret_cast<ushort8*>(C + (size_t)grow * N_DIM + gcol) = v;
    }
  }
#undef STAGE
#undef SB0
#undef SB1
#undef SA0
#undef SA1
#undef LDF
}

// ---------- SRU recurrence, depth-8 software-pipelined loads ----------
__global__ __launch_bounds__(64) void k_rec(
    const unsigned short* __restrict__ xb,  // chunk (Lc, BD) bf16
    const unsigned short* __restrict__ u3,  // chunk (Lc*32, 3072) bf16 planes
    const float* __restrict__ wcv,
    const float* __restrict__ sxp,
    float* __restrict__ c_state,            // (BD)
    float* __restrict__ h,                  // chunk base (Lc, BD) f32
    int Lc)
{
  const int tid = blockIdx.x * 64 + threadIdx.x;
  const int d = tid & (D_DIM - 1);
  const int b = tid >> 10;
  const float fw = wcv[d];
  const float rw = wcv[D_DIM + d];
  const float sx = sxp[0];
  float c = c_state[tid];

  const unsigned short* up = u3 + (size_t)b * N_DIM + d;
  const unsigned short* xp = xb + tid;
  float*                hp = h + tid;

  unsigned short q0[8], q1[8], q2[8], qx[8];
#pragma unroll
  for (int i = 0; i < 8; ++i) {
    q0[i] = up[(size_t)i * S3];
    q1[i] = up[(size_t)i * S3 + 1024];
    q2[i] = up[(size_t)i * S3 + 2048];
    qx[i] = xp[(size_t)i * BD];
  }
  for (int l0 = 0; l0 < Lc; l0 += 8) {
#pragma unroll
    for (int i = 0; i < 8; ++i) {
      const int l = l0 + i;
      float u0 = bf2f(q0[i]);
      float u1 = bf2f(q1[i]);
      float u2 = bf2f(q2[i]);
      float xv = bf2f(qx[i]) * sx;
      const int nl = (l + 8 < Lc) ? (l + 8) : 0;   // wrap: harmless re-read, keeps pipe shape
      q0[i] = up[(size_t)nl * S3];
      q1[i] = up[(size_t)nl * S3 + 1024];
      q2[i] = up[(size_t)nl * S3 + 2048];
      qx[i] = xp[(size_t)nl * BD];
      float f = 1.f / (1.f + __expf(-(u1 + c * fw)));
      float r = 1.f / (1.f + __expf(-(u2 + c * rw)));
      c = u0 + (c - u0) * f;
      hp[(size_t)l * BD] = xv + (c - xv) * r;
    }
  }
  c_state[tid] = c;
}

__global__ void k_copyc(const float* __restrict__ c_state, float* __restrict__ out) {
  int i = blockIdx.x * blockDim.x + threadIdx.x;
  if (i < BD) out[i] = c_state[i];
}

extern "C" void kernel_launch(void* const* d_in, const int* in_sizes, int n_in,
                              void* d_out, int out_size, void* d_ws, size_t ws_size,
                              hipStream_t stream) {
  const float* x    = (const float*)d_in[0];
  const float* w    = (const float*)d_in[1];
  const float* wcv  = (const float*)d_in[2];
  const float* bias = (const float*)d_in[3];
  const float* sx   = (const float*)d_in[4];
  float* hout = (float*)d_out;
  float* cout = hout + (size_t)L_DIM * BD;

  const size_t wt_bytes = (size_t)N_DIM * K_DIM * 2;
  const size_t bc_off   = wt_bytes;
  const size_t c_off    = bc_off + (size_t)N_DIM * 4;
  const size_t xbf_off  = c_off + (size_t)BD * 4;
  int Lc = 8;
  for (int cand : {512, 256, 128, 64, 32, 16, 8}) {
    size_t need = xbf_off + (size_t)cand * 65536 + (size_t)cand * 196608 + 1024;
    if (need <= ws_size) { Lc = cand; break; }
  }
  char* wsb = (char*)d_ws;
  unsigned short* wt_p  = (unsigned short*)wsb;
  float*          bc_p  = (float*)(wsb + bc_off);
  float*          c_p   = (float*)(wsb + c_off);
  unsigned short* xbf_p = (unsigned short*)(wsb + xbf_off);
  unsigned short* u3_p  = (unsigned short*)(wsb + xbf_off + (size_t)Lc * 65536);

  hipMemsetAsync(c_p, 0, (size_t)BD * 4, stream);
  k_wt<<<(K_DIM / 64) * (D_DIM / 64) * 3, 256, 0, stream>>>(w, wt_p);
  k_biascol<<<(N_DIM + 255) / 256, 256, 0, stream>>>(bias, bc_p);

  const int nchunks = L_DIM / Lc;
  const int Mtiles  = (Lc * B_DIM) / 256;
  for (int ci = 0; ci < nchunks; ++ci) {
    const size_t base = (size_t)ci * Lc * BD;
    k_convx<<<(Lc * BD / 8 + 255) / 256, 256, 0, stream>>>(x + base, xbf_p, Lc * BD / 8);
    k_gemm<<<Mtiles * (N_DIM / 256), 512, 0, stream>>>(xbf_p, wt_p, bc_p, u3_p, Mtiles);
    k_rec<<<BD / 64, 64, 0, stream>>>(xbf_p, u3_p, wcv, sx, c_p, hout + base, Lc);
  }
  k_copyc<<<BD / 256, 256, 0, stream>>>(c_p, cout);
}

// Round 5
// 831.410 us; speedup vs baseline: 1.0356x; 1.0356x over previous
//
#include <hip/hip_runtime.h>
#include <stdint.h>

#define L_DIM 2048
#define B_DIM 32
#define D_DIM 1024
#define N_DIM 3072   // 3*D
#define K_DIM 1024
#define BD    32768  // B*D

typedef __bf16 bf16x8 __attribute__((ext_vector_type(8)));
typedef unsigned short ushort8 __attribute__((ext_vector_type(8)));
typedef float f32x4 __attribute__((ext_vector_type(4)));

typedef const __attribute__((address_space(1))) unsigned int* gq_t;
typedef __attribute__((address_space(3))) unsigned int* lq_t;

static __device__ __forceinline__ unsigned short f2bf(float f) {
  unsigned u = __float_as_uint(f);
  u += 0x7FFFu + ((u >> 16) & 1u);   // RNE
  return (unsigned short)(u >> 16);
}

static __device__ __forceinline__ float bf2f(unsigned short s) {
  return __uint_as_float(((unsigned)s) << 16);
}

// ---------- convert x chunk (f32) -> bf16, 8 elems/thread ----------
__global__ void k_convx(const float* __restrict__ x, unsigned short* __restrict__ xb, int n8) {
  int i = blockIdx.x * blockDim.x + threadIdx.x;
  if (i >= n8) return;
  const float4* p = reinterpret_cast<const float4*>(x) + (size_t)i * 2;
  float4 a = p[0], b = p[1];
  ushort8 o;
  o[0] = f2bf(a.x); o[1] = f2bf(a.y); o[2] = f2bf(a.z); o[3] = f2bf(a.w);
  o[4] = f2bf(b.x); o[5] = f2bf(b.y); o[6] = f2bf(b.z); o[7] = f2bf(b.w);
  reinterpret_cast<ushort8*>(xb)[i] = o;
}

// ---------- W (K,N=3072 interleaved 3d+k) f32 -> WT (N'=k*D+d, K) bf16 ----------
__global__ __launch_bounds__(256) void k_wt(const float* __restrict__ w, unsigned short* __restrict__ wt) {
  __shared__ unsigned short tile[64][65];
  const int bid = blockIdx.x;
  const int kb = bid & 15;          // K/64 tile
  const int db = (bid >> 4) & 15;   // D/64 tile
  const int kp = bid >> 8;          // plane 0..2
  const int t = threadIdx.x;
  const int c = t & 63;
  const int q = t >> 6;             // 0..3
#pragma unroll
  for (int i = 0; i < 16; ++i) {
    int r = q * 16 + i;             // k within tile
    float v = w[(size_t)(kb * 64 + r) * N_DIM + 3 * (db * 64 + c) + kp];
    tile[r][c] = f2bf(v);
  }
  __syncthreads();
  const int k = t & 63;
#pragma unroll
  for (int i = 0; i < 16; ++i) {
    int n = q * 16 + i;             // d within tile
    wt[(size_t)(kp * D_DIM + db * 64 + n) * K_DIM + kb * 64 + k] = tile[k][n];
  }
}

// ---------- per-column bias, plane layout: col j = k*D+d ----------
__global__ void k_biascol(const float* __restrict__ bias, float* __restrict__ bc) {
  int j = blockIdx.x * blockDim.x + threadIdx.x;
  if (j >= N_DIM) return;
  int k = j >> 10;
  int d = j & 1023;
  float v = 0.f;
  if (k == 1) v = bias[d];
  else if (k == 2) v = bias[D_DIM + d];
  bc[j] = v;
}

// ---------- 256x256 8-phase bf16 MFMA GEMM (T1..T5 + phase-ahead A-frag pipeline) ----------
__global__ __launch_bounds__(512, 2) void k_gemm(
    const unsigned short* __restrict__ A,
    const unsigned short* __restrict__ BT,
    const float* __restrict__ bc,
    unsigned short* __restrict__ C,
    int Mtiles)
{
  __shared__ unsigned short smem[65536];

  // --- block swizzle (bijective, 8 XCDs) ---
  const int nwg = gridDim.x;
  const int q8 = nwg >> 3, r8 = nwg & 7;
  const int xcd = blockIdx.x & 7, li = blockIdx.x >> 3;
  const int wg = (xcd < r8 ? xcd * (q8 + 1) : r8 * (q8 + 1) + (xcd - r8) * q8) + li;
  const int bm = wg % Mtiles;
  const int bn = wg / Mtiles;

  const int t  = threadIdx.x;
  const int w  = t >> 6;
  const int l  = t & 63;
  const int wr = w >> 2, wc = w & 3;
  const int wrb = wr * 128, wcb = wc * 64;
  const int l15 = l & 15, lg = l >> 4, lx = l & 7;
  const int kgp0 = (lg ^ lx) * 8;          // elem offset of ksub=0 octet
  const int kgp1 = ((4 + lg) ^ lx) * 8;    // ksub=1
  const int sr0 = w * 8 + (l >> 3);        // staging row within half
  const int kgs = (lx ^ (l >> 3)) * 8;     // swizzled source k-octet

  const unsigned short* Abase = A  + (size_t)(bm * 256) * K_DIM;
  const unsigned short* Bbase = BT + (size_t)(bn * 256) * K_DIM;

  f32x4 acc[8][4];
#pragma unroll
  for (int i = 0; i < 8; ++i)
#pragma unroll
    for (int j = 0; j < 4; ++j) acc[i][j] = f32x4{0.f, 0.f, 0.f, 0.f};

#define STAGE(G, growbase, T, ldsBase)                                                  \
  { const unsigned short* s0_ = (G) + (((size_t)((growbase) + sr0)) << 10) + (T) * 64 + kgs; \
    __builtin_amdgcn_global_load_lds((gq_t)s0_, (lq_t)&smem[(ldsBase) + w * 512], 16, 0, 0); \
    const unsigned short* s1_ = s0_ + (64 << 10);                                       \
    __builtin_amdgcn_global_load_lds((gq_t)s1_, (lq_t)&smem[(ldsBase) + 4096 + w * 512], 16, 0, 0); }

#define SB0(T, b) STAGE(Bbase, 0,   (T), (b) * 32768 + 16384)
#define SB1(T, b) STAGE(Bbase, 128, (T), (b) * 32768 + 16384 + 8192)
#define SA0(T, b) STAGE(Abase, 0,   (T), (b) * 32768)
#define SA1(T, b) STAGE(Abase, 128, (T), (b) * 32768 + 8192)

#define LDF(idx) __builtin_bit_cast(bf16x8, *reinterpret_cast<const ushort8*>(&smem[(idx)]))

#define RDA(AF, qq)                                                                     \
  { _Pragma("unroll")                                                                   \
    for (int mf = 0; mf < 2; ++mf) {                                                    \
      const int ar_ = (wrb + ((qq) * 2 + mf) * 16 + l15) * 64;                          \
      AF[mf][0] = LDF(cA + ar_ + kgp0);                                                 \
      AF[mf][1] = LDF(cA + ar_ + kgp1);                                                 \
    } }

#define MFMA_PH(qq, AF)                                                                 \
  { __builtin_amdgcn_s_setprio(1);                                                      \
    _Pragma("unroll")                                                                   \
    for (int mf = 0; mf < 2; ++mf)                                                      \
      _Pragma("unroll")                                                                 \
      for (int nf = 0; nf < 4; ++nf) {                                                  \
        acc[(qq) * 2 + mf][nf] = __builtin_amdgcn_mfma_f32_16x16x32_bf16(AF[mf][0], bfr[nf][0], acc[(qq) * 2 + mf][nf], 0, 0, 0); \
        acc[(qq) * 2 + mf][nf] = __builtin_amdgcn_mfma_f32_16x16x32_bf16(AF[mf][1], bfr[nf][1], acc[(qq) * 2 + mf][nf], 0, 0, 0); \
      }                                                                                 \
    __builtin_amdgcn_s_setprio(0); }

  // ---- prologue: tile0 fully + SB0(1); wait tile0, SB0(1) stays in flight
  SB0(0, 0); SB1(0, 0); SA0(0, 0); SA1(0, 0); SB0(1, 1);
  asm volatile("s_waitcnt vmcnt(2)" ::: "memory");
  __builtin_amdgcn_s_barrier();

#pragma unroll 2
  for (int t0 = 0; t0 < 16; ++t0) {
    const int cur = t0 & 1, nxt = cur ^ 1;
    const int cA = cur * 32768, cB = cA + 16384;
    bf16x8 bfr[4][2], afX[2][2], afY[2][2];

    // ---- phase 0: read B frags + A(q0)->afX + A(q1)->afY; stage SB1(t+1)
#pragma unroll
    for (int nf = 0; nf < 4; ++nf) {
      const int nr = (wcb + nf * 16 + l15) * 64;
      bfr[nf][0] = LDF(cB + nr + kgp0);
      bfr[nf][1] = LDF(cB + nr + kgp1);
    }
    RDA(afX, 0)
    RDA(afY, 1)
    if (t0 < 15) SB1(t0 + 1, nxt);
    __builtin_amdgcn_s_barrier();
    MFMA_PH(0, afX)
    __builtin_amdgcn_s_barrier();
    __builtin_amdgcn_sched_barrier(0);

    // ---- phase 1: prefetch A(q2)->afX; stage SA0(t+1)
    RDA(afX, 2)
    if (t0 < 15) SA0(t0 + 1, nxt);
    __builtin_amdgcn_s_barrier();
    MFMA_PH(1, afY)
    __builtin_amdgcn_s_barrier();
    __builtin_amdgcn_sched_barrier(0);

    // ---- phase 2: prefetch A(q3)->afY; stage SA1(t+1)
    RDA(afY, 3)
    if (t0 < 15) SA1(t0 + 1, nxt);
    __builtin_amdgcn_s_barrier();
    MFMA_PH(2, afX)
    __builtin_amdgcn_s_barrier();
    __builtin_amdgcn_sched_barrier(0);

    // ---- phase 3: stage SB0(t+2)
    if (t0 < 14) SB0(t0 + 2, cur);
    __builtin_amdgcn_s_barrier();
    MFMA_PH(3, afY)
    if (t0 < 14)       asm volatile("s_waitcnt vmcnt(2)" ::: "memory");
    else if (t0 == 14) asm volatile("s_waitcnt vmcnt(0)" ::: "memory");
    __builtin_amdgcn_s_barrier();
    __builtin_amdgcn_sched_barrier(0);
  }

  // ---- epilogue (r3 form): bias add, f32->bf16, scalar stores
  const int r4 = lg * 4;
  float badd[4];
#pragma unroll
  for (int nf = 0; nf < 4; ++nf) badd[nf] = bc[bn * 256 + wcb + nf * 16 + l15];
#pragma unroll
  for (int fm = 0; fm < 8; ++fm) {
    const int row = bm * 256 + wrb + fm * 16 + r4;
#pragma unroll
    for (int nf = 0; nf < 4; ++nf) {
      const int col = bn * 256 + wcb + nf * 16 + l15;
      unsigned short* out = C + (size_t)row * N_DIM + col;
#pragma unroll
      for (int i = 0; i < 4; ++i)
        out[(size_t)i * N_DIM] = f2bf(acc[fm][nf][i] + badd[nf]);
    }
  }
#undef STAGE
#undef SB0
#undef SB1
#undef SA0
#undef SA1
#undef LDF
#undef RDA
#undef MFMA_PH
}

// ---------- SRU recurrence over a chunk of Lc steps (r3 form) ----------
__global__ void k_rec(const unsigned short* __restrict__ xb,  // chunk (Lc, BD) bf16
                      const unsigned short* __restrict__ u3,  // chunk (Lc*32, 3072) bf16 planes
                      const float* __restrict__ wcv,
                      const float* __restrict__ sxp,
                      float* __restrict__ c_state,            // (BD)
                      float* __restrict__ h,                  // chunk base (Lc, BD) f32
                      int Lc)
{
  int tid = blockIdx.x * blockDim.x + threadIdx.x;
  if (tid >= BD) return;
  const int d = tid & (D_DIM - 1);
  const int b = tid >> 10;
  const float fw = wcv[d];
  const float rw = wcv[D_DIM + d];
  const float sx = sxp[0];
  float c = c_state[tid];

  const unsigned short* up = u3 + (size_t)b * N_DIM + d;
  const unsigned short* xp = xb + tid;
  float*                hp = h + tid;

#pragma unroll 8
  for (int l = 0; l < Lc; ++l) {
    float u0 = bf2f(up[0]);
    float u1 = bf2f(up[1024]);
    float u2 = bf2f(up[2048]);
    float xv = bf2f(xp[0]) * sx;
    float f = 1.f / (1.f + __expf(-(u1 + c * fw)));
    float r = 1.f / (1.f + __expf(-(u2 + c * rw)));
    c = u0 + (c - u0) * f;
    hp[0] = xv + (c - xv) * r;
    up += (size_t)32 * N_DIM;
    xp += BD;
    hp += BD;
  }
  c_state[tid] = c;
}

__global__ void k_copyc(const float* __restrict__ c_state, float* __restrict__ out) {
  int i = blockIdx.x * blockDim.x + threadIdx.x;
  if (i < BD) out[i] = c_state[i];
}

extern "C" void kernel_launch(void* const* d_in, const int* in_sizes, int n_in,
                              void* d_out, int out_size, void* d_ws, size_t ws_size,
                              hipStream_t stream) {
  const float* x    = (const float*)d_in[0];
  const float* w    = (const float*)d_in[1];
  const float* wcv  = (const float*)d_in[2];
  const float* bias = (const float*)d_in[3];
  const float* sx   = (const float*)d_in[4];
  float* hout = (float*)d_out;
  float* cout = hout + (size_t)L_DIM * BD;

  const size_t wt_bytes = (size_t)N_DIM * K_DIM * 2;
  const size_t bc_off   = wt_bytes;
  const size_t c_off    = bc_off + (size_t)N_DIM * 4;
  const size_t xbf_off  = c_off + (size_t)BD * 4;
  int Lc = 8;
  for (int cand : {512, 256, 128, 64, 32, 16, 8}) {
    size_t need = xbf_off + (size_t)cand * 65536 + (size_t)cand * 196608 + 1024;
    if (need <= ws_size) { Lc = cand; break; }
  }
  char* wsb = (char*)d_ws;
  unsigned short* wt_p  = (unsigned short*)wsb;
  float*          bc_p  = (float*)(wsb + bc_off);
  float*          c_p   = (float*)(wsb + c_off);
  unsigned short* xbf_p = (unsigned short*)(wsb + xbf_off);
  unsigned short* u3_p  = (unsigned short*)(wsb + xbf_off + (size_t)Lc * 65536);

  hipMemsetAsync(c_p, 0, (size_t)BD * 4, stream);
  k_wt<<<(K_DIM / 64) * (D_DIM / 64) * 3, 256, 0, stream>>>(w, wt_p);
  k_biascol<<<(N_DIM + 255) / 256, 256, 0, stream>>>(bias, bc_p);

  const int nchunks = L_DIM / Lc;
  const int Mtiles  = (Lc * B_DIM) / 256;
  for (int ci = 0; ci < nchunks; ++ci) {
    const size_t base = (size_t)ci * Lc * BD;
    k_convx<<<(Lc * BD / 8 + 255) / 256, 256, 0, stream>>>(x + base, xbf_p, Lc * BD / 8);
    k_gemm<<<Mtiles * (N_DIM / 256), 512, 0, stream>>>(xbf_p, wt_p, bc_p, u3_p, Mtiles);
    k_rec<<<BD / 64, 64, 0, stream>>>(xbf_p, u3_p, wcv, sx, c_p, hout + base, Lc);
  }
  k_copyc<<<BD / 256, 256, 0, stream>>>(c_p, cout);
}